// Round 1
// baseline (69.790 us; speedup 1.0000x reference)
//
#include <hip/hip_runtime.h>

#define N_ROIS 2048
#define N_CLSX 21
#define SCORE_T 0.3f
#define NMS_T 0.3f
#define DEDUP_T 0.3f
#define NT 1024

// Map float to uint such that ascending uint order == ascending float order.
__device__ __forceinline__ unsigned f2ord(float f) {
    unsigned u = __float_as_uint(f);
    return (u & 0x80000000u) ? ~u : (u | 0x80000000u);
}

__global__ __launch_bounds__(NT) void detect_kernel(
    const float* __restrict__ rois,      // (2048,5)  [batch 0]
    const float* __restrict__ cls_prob,  // (2048,21)
    const float* __restrict__ bbox_pred, // (2048,84)
    const float* __restrict__ im_info,   // (3,)
    const float* __restrict__ gt_boxes,  // (50,5)
    const int*   __restrict__ num_boxes, // scalar
    float* __restrict__ out)             // (20,2048,5)
{
    __shared__ unsigned long long skey[N_ROIS];
    __shared__ float bx1[N_ROIS], by1[N_ROIS], bx2[N_ROIS], by2[N_ROIS];
    __shared__ float ssc[N_ROIS];
    __shared__ unsigned char keep[N_ROIS];
    __shared__ int nvalid;

    const int tid = threadIdx.x;
    const int cls = blockIdx.x + 1;   // original class index 1..20

    if (tid == 0) nvalid = 0;

    // ---- phase 0: build composite sort keys (stable argsort of valid?-s:+inf)
    for (int i = tid; i < N_ROIS; i += NT) {
        float sc = cls_prob[i * N_CLSX + cls];
        bool valid = sc > SCORE_T;
        float keyf = valid ? -sc : __int_as_float(0x7f800000); // +inf
        unsigned kb = f2ord(keyf);
        skey[i] = ((unsigned long long)kb << 32) | (unsigned)i;
    }
    __syncthreads();

    // ---- phase 1: bitonic sort ascending (2048 elements, pairs are disjoint
    // within a pass so the 2-elements-per-thread loop needs no inner barrier)
    for (unsigned k = 2; k <= N_ROIS; k <<= 1) {
        for (unsigned j = k >> 1; j > 0; j >>= 1) {
            for (unsigned i = tid; i < N_ROIS; i += NT) {
                unsigned ixj = i ^ j;
                if (ixj > i) {
                    unsigned long long a = skey[i], b = skey[ixj];
                    bool up = ((i & k) == 0);
                    if ((a > b) == up) { skey[i] = b; skey[ixj] = a; }
                }
            }
            __syncthreads();
        }
    }

    // ---- phase 2: gather in sorted order + decode + clip
    const float W = im_info[1], H = im_info[0];
    for (int j = tid; j < N_ROIS; j += NT) {
        int idx = (int)(skey[j] & 0xFFFFFFFFu);
        float x1 = rois[idx * 5 + 1], y1 = rois[idx * 5 + 2];
        float x2 = rois[idx * 5 + 3], y2 = rois[idx * 5 + 4];
        float w = x2 - x1 + 1.0f, h = y2 - y1 + 1.0f;
        float cx = x1 + 0.5f * w, cy = y1 + 0.5f * h;
        const float* d = &bbox_pred[idx * (4 * N_CLSX) + cls * 4];
        float dx = d[0] * 0.1f, dy = d[1] * 0.1f;
        float dw = d[2] * 0.2f, dh = d[3] * 0.2f;
        float pcx = dx * w + cx, pcy = dy * h + cy;
        float pw = expf(dw) * w, ph = expf(dh) * h;
        float nx1 = fminf(fmaxf(pcx - 0.5f * pw, 0.0f), W - 1.0f);
        float ny1 = fminf(fmaxf(pcy - 0.5f * ph, 0.0f), H - 1.0f);
        float nx2 = fminf(fmaxf(pcx + 0.5f * pw, 0.0f), W - 1.0f);
        float ny2 = fminf(fmaxf(pcy + 0.5f * ph, 0.0f), H - 1.0f);
        bx1[j] = nx1; by1[j] = ny1; bx2[j] = nx2; by2[j] = ny2;
        float sc = cls_prob[idx * N_CLSX + cls];
        ssc[j] = sc;
        bool valid = sc > SCORE_T;
        keep[j] = valid ? 1 : 0;
        if (valid) atomicAdd(&nvalid, 1);
    }
    __syncthreads();
    const int nv = nvalid;

    // ---- phase 3: greedy NMS in sorted order (valid boxes occupy [0, nv))
    for (int i = 0; i < nv; ++i) {
        __syncthreads();
        if (keep[i]) {
            float ax1 = bx1[i], ay1 = by1[i], ax2 = bx2[i], ay2 = by2[i];
            float aarea = (ax2 - ax1) * (ay2 - ay1);
            for (int j = i + 1 + tid; j < nv; j += NT) {
                if (keep[j]) {
                    float ix1 = fmaxf(ax1, bx1[j]);
                    float iy1 = fmaxf(ay1, by1[j]);
                    float ix2 = fminf(ax2, bx2[j]);
                    float iy2 = fminf(ay2, by2[j]);
                    float iw = fmaxf(ix2 - ix1, 0.0f);
                    float ih = fmaxf(iy2 - iy1, 0.0f);
                    float inter = iw * ih;
                    float barea = (bx2[j] - bx1[j]) * (by2[j] - by1[j]);
                    float iou = inter / (aarea + barea - inter + 1e-6f);
                    if (iou > NMS_T) keep[j] = 0;
                }
            }
        }
    }
    __syncthreads();

    // ---- phase 4: GT dedup (any IoU vs gt > 0.3 -> drop)
    const int ng = *num_boxes;
    for (int j = tid; j < nv; j += NT) {
        if (keep[j]) {
            float ax1 = bx1[j], ay1 = by1[j], ax2 = bx2[j], ay2 = by2[j];
            float aarea = (ax2 - ax1) * (ay2 - ay1);
            bool dup = false;
            for (int g = 0; g < ng; ++g) {
                float gx1 = gt_boxes[g * 5 + 0], gy1 = gt_boxes[g * 5 + 1];
                float gx2 = gt_boxes[g * 5 + 2], gy2 = gt_boxes[g * 5 + 3];
                float garea = (gx2 - gx1) * (gy2 - gy1);
                float ix1 = fmaxf(ax1, gx1);
                float iy1 = fmaxf(ay1, gy1);
                float ix2 = fminf(ax2, gx2);
                float iy2 = fminf(ay2, gy2);
                float iw = fmaxf(ix2 - ix1, 0.0f);
                float ih = fmaxf(iy2 - iy1, 0.0f);
                float inter = iw * ih;
                float iou = inter / (aarea + garea - inter + 1e-6f);
                if (iou > DEDUP_T) { dup = true; break; }
            }
            if (dup) keep[j] = 0;
        }
    }
    __syncthreads();

    // ---- phase 5: masked write in sorted order
    float* o = out + (size_t)blockIdx.x * N_ROIS * 5;
    for (int j = tid; j < N_ROIS; j += NT) {
        bool m = keep[j] != 0;
        o[j * 5 + 0] = m ? bx1[j] : 0.0f;
        o[j * 5 + 1] = m ? by1[j] : 0.0f;
        o[j * 5 + 2] = m ? bx2[j] : 0.0f;
        o[j * 5 + 3] = m ? by2[j] : 0.0f;
        o[j * 5 + 4] = m ? ssc[j] : 0.0f;
    }
}

extern "C" void kernel_launch(void* const* d_in, const int* in_sizes, int n_in,
                              void* d_out, int out_size, void* d_ws, size_t ws_size,
                              hipStream_t stream) {
    const float* rois      = (const float*)d_in[0];
    const float* cls_prob  = (const float*)d_in[1];
    const float* bbox_pred = (const float*)d_in[2];
    const float* im_info   = (const float*)d_in[3];
    const float* gt        = (const float*)d_in[4];
    const int*   nb        = (const int*)d_in[5];
    float* out = (float*)d_out;

    detect_kernel<<<dim3(20), dim3(NT), 0, stream>>>(
        rois, cls_prob, bbox_pred, im_info, gt, nb, out);
}

// Round 2
// 43.215 us; speedup vs baseline: 1.6149x; 1.6149x over previous
//
#include <hip/hip_runtime.h>

#define N_ROIS 2048
#define N_CLSX 21
#define SCORE_T 0.3f
#define NMS_T 0.3f
#define DEDUP_T 0.3f
#define NT 256
#define NVMAX 512
#define NWMAX (NVMAX / 64)   // 8 words per suppression row

__global__ __launch_bounds__(NT) void detect_kernel(
    const float* __restrict__ rois,      // (2048,5)  [batch 0]
    const float* __restrict__ cls_prob,  // (2048,21)
    const float* __restrict__ bbox_pred, // (2048,84)
    const float* __restrict__ im_info,   // (3,)
    const float* __restrict__ gt_boxes,  // (50,5)
    const int*   __restrict__ num_boxes, // scalar
    float* __restrict__ out)             // (20,2048,5)
{
    __shared__ float vsc[N_ROIS];
    __shared__ int   vidx[N_ROIS];
    __shared__ float sbx1[N_ROIS], sby1[N_ROIS], sbx2[N_ROIS], sby2[N_ROIS];
    __shared__ float ssc[N_ROIS];
    __shared__ unsigned long long supmat[NVMAX * NWMAX]; // row i: bits j>i with iou>T
    __shared__ unsigned long long kwords[32];
    __shared__ unsigned char keepb[N_ROIS];
    __shared__ float sgt[50 * 4];
    __shared__ int nvalid;

    const int tid = threadIdx.x;
    const int cls = blockIdx.x + 1;   // original class index 1..20
    const int ng  = *num_boxes;

    if (tid == 0) nvalid = 0;
    __syncthreads();

    // ---- phase A: valid test + compaction (order irrelevant; ranked later)
    for (int i = tid; i < N_ROIS; i += NT) {
        float sc = cls_prob[i * N_CLSX + cls];
        if (sc > SCORE_T) {
            int pos = atomicAdd(&nvalid, 1);
            vidx[pos] = i;
            vsc[pos]  = sc;
        }
    }
    // stage gt boxes (x1,y1,x2,y2 of each row of 5)
    for (int t = tid; t < ng * 4; t += NT) {
        int g = t >> 2, c = t & 3;
        sgt[t] = gt_boxes[g * 5 + c];
    }
    __syncthreads();
    const int nv = nvalid;

    // ---- phase B: rank (descending score, ties by ascending roi idx) +
    //               decode + clip, scatter into sorted position
    const float W = im_info[1], H = im_info[0];
    for (int v = tid; v < nv; v += NT) {
        int idx = vidx[v];
        float sc = vsc[v];
        int r = 0;
        for (int u = 0; u < nv; ++u) {
            float su = vsc[u];
            r += (su > sc) || (su == sc && vidx[u] < idx);
        }
        float x1 = rois[idx * 5 + 1], y1 = rois[idx * 5 + 2];
        float x2 = rois[idx * 5 + 3], y2 = rois[idx * 5 + 4];
        float w = x2 - x1 + 1.0f, h = y2 - y1 + 1.0f;
        float cx = x1 + 0.5f * w, cy = y1 + 0.5f * h;
        const float* d = &bbox_pred[idx * (4 * N_CLSX) + cls * 4];
        float dx = d[0] * 0.1f, dy = d[1] * 0.1f;
        float dw = d[2] * 0.2f, dh = d[3] * 0.2f;
        float pcx = dx * w + cx, pcy = dy * h + cy;
        float pw = expf(dw) * w, ph = expf(dh) * h;
        sbx1[r] = fminf(fmaxf(pcx - 0.5f * pw, 0.0f), W - 1.0f);
        sby1[r] = fminf(fmaxf(pcy - 0.5f * ph, 0.0f), H - 1.0f);
        sbx2[r] = fminf(fmaxf(pcx + 0.5f * pw, 0.0f), W - 1.0f);
        sby2[r] = fminf(fmaxf(pcy + 0.5f * ph, 0.0f), H - 1.0f);
        ssc[r]  = sc;
        keepb[r] = 1;   // used by fallback path; overwritten in phase E
    }
    __syncthreads();

    const int NW = (nv + 63) >> 6;

    if (nv <= NVMAX) {
        // ---- phase C: suppression bit-matrix, one 64-col word per wave task
        const int wid = tid >> 6, lane = tid & 63;
        const int nwaves = NT / 64;
        for (int task = wid; task < nv * NW; task += nwaves) {
            int i = task / NW;
            int w = task - i * NW;
            float ax1 = sbx1[i], ay1 = sby1[i], ax2 = sbx2[i], ay2 = sby2[i];
            float aarea = (ax2 - ax1) * (ay2 - ay1);
            int j = (w << 6) + lane;
            bool bit = false;
            if (j < nv && j > i) {
                float ix1 = fmaxf(ax1, sbx1[j]);
                float iy1 = fmaxf(ay1, sby1[j]);
                float ix2 = fminf(ax2, sbx2[j]);
                float iy2 = fminf(ay2, sby2[j]);
                float iw = fmaxf(ix2 - ix1, 0.0f);
                float ih = fmaxf(iy2 - iy1, 0.0f);
                float inter = iw * ih;
                float barea = (sbx2[j] - sbx1[j]) * (sby2[j] - sby1[j]);
                float iou = inter / (aarea + barea - inter + 1e-6f);
                bit = iou > NMS_T;
            }
            unsigned long long word = __ballot(bit);
            if (lane == 0) supmat[task] = word;
        }
        __syncthreads();

        // ---- phase D: greedy reduction on a single wave, no barriers
        if (tid < 64) {
            int lane = tid;
            int rem = nv - (lane << 6);
            unsigned long long kw =
                (lane < NW) ? ((rem >= 64) ? ~0ULL : ((1ULL << rem) - 1ULL))
                            : 0ULL;
            for (int i = 0; i < nv; ++i) {
                unsigned long long kwi = __shfl(kw, i >> 6);
                if ((kwi >> (i & 63)) & 1ULL) {
                    unsigned long long s =
                        (lane < NW) ? supmat[i * NW + lane] : 0ULL;
                    kw &= ~s;
                }
            }
            if (lane < 32) kwords[lane] = kw;
        }
        __syncthreads();
    } else {
        // ---- fallback (nv > NVMAX): barrier-per-row greedy NMS
        for (int i = 0; i < nv; ++i) {
            __syncthreads();
            if (keepb[i]) {
                float ax1 = sbx1[i], ay1 = sby1[i], ax2 = sbx2[i], ay2 = sby2[i];
                float aarea = (ax2 - ax1) * (ay2 - ay1);
                for (int j = i + 1 + tid; j < nv; j += NT) {
                    if (keepb[j]) {
                        float ix1 = fmaxf(ax1, sbx1[j]);
                        float iy1 = fmaxf(ay1, sby1[j]);
                        float ix2 = fminf(ax2, sbx2[j]);
                        float iy2 = fminf(ay2, sby2[j]);
                        float iw = fmaxf(ix2 - ix1, 0.0f);
                        float ih = fmaxf(iy2 - iy1, 0.0f);
                        float inter = iw * ih;
                        float barea = (sbx2[j] - sbx1[j]) * (sby2[j] - sby1[j]);
                        float iou = inter / (aarea + barea - inter + 1e-6f);
                        if (iou > NMS_T) keepb[j] = 0;
                    }
                }
            }
        }
        __syncthreads();
    }

    // ---- phase E: GT dedup; finalize keepb
    for (int v = tid; v < nv; v += NT) {
        bool kept = (nv <= NVMAX)
                        ? (bool)((kwords[v >> 6] >> (v & 63)) & 1ULL)
                        : (bool)keepb[v];
        bool dup = false;
        if (kept) {
            float ax1 = sbx1[v], ay1 = sby1[v], ax2 = sbx2[v], ay2 = sby2[v];
            float aarea = (ax2 - ax1) * (ay2 - ay1);
            for (int g = 0; g < ng; ++g) {
                float gx1 = sgt[g * 4 + 0], gy1 = sgt[g * 4 + 1];
                float gx2 = sgt[g * 4 + 2], gy2 = sgt[g * 4 + 3];
                float garea = (gx2 - gx1) * (gy2 - gy1);
                float ix1 = fmaxf(ax1, gx1);
                float iy1 = fmaxf(ay1, gy1);
                float ix2 = fminf(ax2, gx2);
                float iy2 = fminf(ay2, gy2);
                float iw = fmaxf(ix2 - ix1, 0.0f);
                float ih = fmaxf(iy2 - iy1, 0.0f);
                float inter = iw * ih;
                float iou = inter / (aarea + garea - inter + 1e-6f);
                if (iou > DEDUP_T) { dup = true; break; }
            }
        }
        keepb[v] = (kept && !dup) ? 1 : 0;
    }
    __syncthreads();

    // ---- phase F: write output rows (zeros where not kept / beyond nv)
    float* o = out + (size_t)blockIdx.x * N_ROIS * 5;
    for (int j = tid; j < N_ROIS; j += NT) {
        bool m = (j < nv) && (keepb[j] != 0);
        o[j * 5 + 0] = m ? sbx1[j] : 0.0f;
        o[j * 5 + 1] = m ? sby1[j] : 0.0f;
        o[j * 5 + 2] = m ? sbx2[j] : 0.0f;
        o[j * 5 + 3] = m ? sby2[j] : 0.0f;
        o[j * 5 + 4] = m ? ssc[j]  : 0.0f;
    }
}

extern "C" void kernel_launch(void* const* d_in, const int* in_sizes, int n_in,
                              void* d_out, int out_size, void* d_ws, size_t ws_size,
                              hipStream_t stream) {
    const float* rois      = (const float*)d_in[0];
    const float* cls_prob  = (const float*)d_in[1];
    const float* bbox_pred = (const float*)d_in[2];
    const float* im_info   = (const float*)d_in[3];
    const float* gt        = (const float*)d_in[4];
    const int*   nb        = (const int*)d_in[5];
    float* out = (float*)d_out;

    detect_kernel<<<dim3(20), dim3(NT), 0, stream>>>(
        rois, cls_prob, bbox_pred, im_info, gt, nb, out);
}